// Round 6
// baseline (9267.930 us; speedup 1.0000x reference)
//
#include <hip/hip_runtime.h>

// ComplexModel: 2-layer LSTM (B=64,T=256,D=512,H=1024) + FC head, MI355X gfx950.
// R6: strip the per-step chain to the bare recurrence.
//  - x-part gates precomputed as GEMMs into xg[t][blk][tid] (half4, MFMA C-layout):
//    xg1 = x@W1+b1 before lstm1; xg2 = ys1@W2+b2 between lstm1 and lstm2 (ys1 is
//    fully materialized then). The recurrent kernel streams NO weights.
//  - barrier-free step loop: gate regroup, cell update, publish are all WAVE-LOCAL
//    (4c+g permute puts a cell's i/f/g/o and rows in one wave). No __syncthreads in
//    the loop; each wave publishes its own 128B patch (sc1) + bumps the block counter.
//  - consumers poll per-block counters (>= 4t) per-wave; h loads plain cached
//    (single-writer lines, read-after-flag, startup acquire purges stale L2).

#define NT 256

typedef _Float16 f16x8 __attribute__((ext_vector_type(8)));
typedef _Float16 f16x4 __attribute__((ext_vector_type(4)));
typedef float f32x4 __attribute__((ext_vector_type(4)));
typedef unsigned long long u64;

__device__ __forceinline__ float sigm(float x)   { return 1.0f / (1.0f + __expf(-x)); }
__device__ __forceinline__ float tanh_f(float x) { return 1.0f - 2.0f / (__expf(2.0f * x) + 1.0f); }

// ---------------- prep kernels ----------------

// x [b][t][d] fp32 -> xh tiled f16: xh[t][dg=d/8][b][d%8]
__global__ void prep_x_kernel(const float* __restrict__ x, _Float16* __restrict__ xh) {
  int id = blockIdx.x * blockDim.x + threadIdx.x;   // 64*256*512
  int j = id & 7, b = (id >> 3) & 63, cg = (id >> 9) & 63, t = id >> 15;
  xh[id] = (_Float16)x[((size_t)b * 256 + t) * 512 + cg * 8 + j];
}

// Build MFMA B-fragment layout: dst[((nt*(K/32)+kb)*64 + lane)*8 + j] =
//   src[k = kb*32 + (lane>>4)*8 + j][col = perm(nt*16 + (lane&15))]
__global__ void swizzle_b_kernel(const float* __restrict__ src0, const float* __restrict__ src1,
                                 int k0, int K, int N, int srcStride, int permute,
                                 _Float16* __restrict__ dst) {
  int id = blockIdx.x * blockDim.x + threadIdx.x;
  int total = (N / 16) * (K / 32) * 64;
  if (id >= total) return;
  int lane = id & 63;
  int kb = (id >> 6) % (K / 32);
  int nt = id / ((K / 32) * 64);
  int kbase = kb * 32 + ((lane >> 4) << 3);
  int pc = nt * 16 + (lane & 15);
  int oc = permute ? ((pc & 3) * 1024 + (pc >> 2)) : pc;   // pc = 4*hcol + gate
  f16x8 v;
  #pragma unroll
  for (int j = 0; j < 8; ++j) {
    int k = kbase + j;
    float f = (k < k0) ? src0[(size_t)k * srcStride + oc]
                       : src1[(size_t)(k - k0) * srcStride + oc];
    v[j] = (_Float16)f;
  }
  ((f16x8*)dst)[id] = v;
}

__global__ void prep_small_kernel(const float* __restrict__ b1, const float* __restrict__ b2,
                                  const float* __restrict__ h0,
                                  float* __restrict__ b1p, float* __restrict__ b2p,
                                  _Float16* __restrict__ ys1_0, int* __restrict__ bar) {
  int i = blockIdx.x * blockDim.x + threadIdx.x;
  if (i < 4096) {
    int oc = (i & 3) * 1024 + (i >> 2);
    b1p[i] = b1[oc];
    b2p[i] = b2[oc];
  }
  if (i < 65536) {  // h0 [b][1024] -> tiled [cg][b][8]
    int j = i & 7, b = (i >> 3) & 63, cg = i >> 9;
    ys1_0[i] = (_Float16)h0[b * 1024 + cg * 8 + j];
  }
  if (i < 8192) bar[i] = 0;
}

// ---------------- x-part gate GEMM ----------------
// xg[((t*256 + gb)*256 + w*64 + lane)] (half4) = x-part pre-activation in the exact
// MFMA C-layout the lstm kernel's wave w / lane expects. gb == lstm blockIdx.
// Grid 512 = btc(2: t-halves) x gb(256). Wave w handles t = btc*128 + 4i + w.
__launch_bounds__(256, 2)
__global__ void xg_gemm_kernel(const _Float16* __restrict__ xsrc, size_t xts, int kxb,
                               const _Float16* __restrict__ bfrag, const float* __restrict__ biasp,
                               _Float16* __restrict__ xg) {
  __shared__ _Float16 Bs[2 * 32 * 64 * 8];   // 64 KB max (kxb<=32), 2 n-tiles
  const int tid = threadIdx.x;
  const int lane = tid & 63;
  const int w = tid >> 6;
  const int btc = blockIdx.x >> 8;
  const int gb = blockIdx.x & 255;
  const int mb = gb & 1, nb = gb >> 1;
  const int KB = kxb + 32;
  if (tid == 0)  // purge stale L2 lines (pre-dispatch poison) before cached reads
    (void)__hip_atomic_load((const int*)biasp, __ATOMIC_ACQUIRE, __HIP_MEMORY_SCOPE_AGENT);
  __syncthreads();
  #pragma unroll
  for (int h = 0; h < 2; ++h) {
    const uint4* s = (const uint4*)bfrag + (size_t)((2 * nb + h) * KB) * 64;  // x-part
    uint4* d = (uint4*)Bs + h * 2048;
    for (int i = tid; i < kxb * 64; i += NT) d[i] = s[i];
  }
  __syncthreads();
  const f16x8* Bv = (const f16x8*)Bs;
  const int q = lane >> 4;
  const float bias0 = biasp[(2 * nb + 0) * 16 + (lane & 15)];
  const float bias1 = biasp[(2 * nb + 1) * 16 + (lane & 15)];
  for (int i = 0; i < 32; ++i) {
    int t = btc * 128 + i * 4 + w;
    const f16x8* ax = (const f16x8*)(xsrc + (size_t)t * xts);
    f32x4 acc[4];  // tile index w' = (wn'<<1)|wm'
    acc[0] = (f32x4){bias0, bias0, bias0, bias0};
    acc[1] = (f32x4){bias0, bias0, bias0, bias0};
    acc[2] = (f32x4){bias1, bias1, bias1, bias1};
    acc[3] = (f32x4){bias1, bias1, bias1, bias1};
    #pragma unroll 8
    for (int kb = 0; kb < kxb; ++kb) {
      f16x8 a0 = ax[(kb * 4 + q) * 64 + mb * 32 + (lane & 15)];
      f16x8 a1 = ax[(kb * 4 + q) * 64 + mb * 32 + 16 + (lane & 15)];
      f16x8 b0 = Bv[kb * 64 + lane];
      f16x8 b1v = Bv[2048 + kb * 64 + lane];
      acc[0] = __builtin_amdgcn_mfma_f32_16x16x32_f16(a0, b0, acc[0], 0, 0, 0);
      acc[1] = __builtin_amdgcn_mfma_f32_16x16x32_f16(a1, b0, acc[1], 0, 0, 0);
      acc[2] = __builtin_amdgcn_mfma_f32_16x16x32_f16(a0, b1v, acc[2], 0, 0, 0);
      acc[3] = __builtin_amdgcn_mfma_f32_16x16x32_f16(a1, b1v, acc[3], 0, 0, 0);
    }
    #pragma unroll
    for (int wp = 0; wp < 4; ++wp) {
      f16x4 hv;
      #pragma unroll
      for (int j = 0; j < 4; ++j) hv[j] = (_Float16)acc[wp][j];
      ((f16x4*)xg)[((size_t)t * 256 + gb) * 256 + wp * 64 + lane] = hv;
    }
  }
}

// ---------------- persistent LSTM layer (recurrence only) ----------------
// Grid 256 = mb(2) x nb(128). Block: batches [32mb,+32) x hcols [8nb,+8).
// Waves: wm=w&1 (m-tile), wn=w>>1 (n-tile). h slot layout: [cg=col/8][b][col%8].
// Per-wave cell mapping: lane -> (b4=lane>>2 within wm's 16 batches, c=lane&3 within
// wn's 4 hcols). Flags: bar[mb*128+nb] counter, +=1 per wave per step (target 4t).
__launch_bounds__(NT, 1)
__global__ void lstm_layer_kernel(const _Float16* __restrict__ xg,
                                  _Float16* hseq, const _Float16* __restrict__ hinit,
                                  const _Float16* __restrict__ bfrag, int kxb,
                                  const float* __restrict__ cin, float* __restrict__ cout,
                                  int* bar) {
  __shared__ _Float16 Bs[2 * 32 * 64 * 8];            // 64 KB U-part B fragments
  __shared__ __align__(16) float gt[4][16 * 20];      // per-wave gate tile (pad 20)
  __shared__ u64 hl[4][16];                           // per-wave h staging (128 B)
  const int tid = threadIdx.x;
  const int lane = tid & 63;
  const int w = tid >> 6;
  const int wm = w & 1, wn = w >> 1;
  const int blk = blockIdx.x;
  const int mb = blk & 1, nb = blk >> 1;
  const int KB = kxb + 32;

  if (tid == 0)  // purge stale L2 (poison / cross-dispatch) before cached reads
    (void)__hip_atomic_load(&bar[1024], __ATOMIC_ACQUIRE, __HIP_MEMORY_SCOPE_AGENT);
  __syncthreads();

  #pragma unroll
  for (int h = 0; h < 2; ++h) {  // stage U-part fragments
    const uint4* s = (const uint4*)bfrag + (size_t)((2 * nb + h) * KB + kxb) * 64;
    uint4* d = (uint4*)Bs + h * 2048;
    for (int i = tid; i < 2048; i += NT) d[i] = s[i];
  }
  __syncthreads();

  const f16x8* Bv = (const f16x8*)Bs;
  const int q = lane >> 4;
  const int brow = mb * 32 + wm * 16 + (lane & 15);   // A row (batch) this lane supplies
  float cc = cin[(size_t)(mb * 32 + wm * 16 + (lane >> 2)) * 1024 + nb * 8 + wn * 4 + (lane & 3)];
  float* gw = &gt[w][0];
  _Float16* hw = (_Float16*)&hl[w][0];
  const u64 hstIdx = (u64)(nb * 128 + (mb * 32 + wm * 16 + (lane & 15)) * 2 + wn);
  const u64* fp = (const u64*)bar + mb * 64 + lane;   // 128 counters of this half
  const int cidx = mb * 128 + nb;

  for (int t = 0; t < 256; ++t) {
    f16x4 xgv = ((const f16x4*)xg)[((size_t)t * 256 + blk) * 256 + w * 64 + lane];  // prefetch
    if (t) {
      int tgt = t << 2;
      for (;;) {
        u64 v = __hip_atomic_load(fp, __ATOMIC_RELAXED, __HIP_MEMORY_SCOPE_AGENT);
        if (__all(((int)v >= tgt) && ((int)(v >> 32) >= tgt))) break;
        __builtin_amdgcn_s_sleep(1);
      }
      asm volatile("" ::: "memory");  // keep h loads below the poll
    }
    f32x4 acc = {(float)xgv[0], (float)xgv[1], (float)xgv[2], (float)xgv[3]};
    const f16x8* ah = (const f16x8*)((t == 0) ? hinit : (hseq + (size_t)t * 65536));
    #pragma unroll 8
    for (int kb = 0; kb < 32; ++kb)
      acc = __builtin_amdgcn_mfma_f32_16x16x32_f16(ah[(kb * 4 + q) * 64 + brow],
                                                   Bv[(wn * 32 + kb) * 64 + lane], acc, 0, 0, 0);
    // wave-local gate regroup: write C rows, read this lane's cell (i,f,g,o)
    #pragma unroll
    for (int r = 0; r < 4; ++r) gw[(q * 4 + r) * 20 + (lane & 15)] = acc[r];
    float4 gv = *(float4*)&gw[(lane >> 2) * 20 + (lane & 3) * 4];
    cc = sigm(gv.y) * cc + sigm(gv.x) * tanh_f(gv.z);
    float hn = sigm(gv.w) * tanh_f(cc);
    hw[lane] = (_Float16)hn;                          // hw[4*b4 + c]
    u64 hv = hl[w][lane & 15];                        // 8B = cols [wn*4,+4) of batch (lane&15)
    if (lane < 16)
      __hip_atomic_store((u64*)(hseq + (size_t)(t + 1) * 65536) + hstIdx, hv,
                         __ATOMIC_RELAXED, __HIP_MEMORY_SCOPE_AGENT);
    __builtin_amdgcn_s_waitcnt(0);                    // drain this wave's h stores
    asm volatile("" ::: "memory");
    if (lane == 0)
      (void)__hip_atomic_fetch_add(&bar[cidx], 1, __ATOMIC_RELAXED, __HIP_MEMORY_SCOPE_AGENT);
  }
  if (cout)
    cout[(size_t)(mb * 32 + wm * 16 + (lane >> 2)) * 1024 + nb * 8 + wn * 4 + (lane & 3)] = cc;
}

// ---------------- FC head ----------------

// Y1[b][u][j] = ys2[u+1][b][:] @ fc1_w[:, j] + fc1_b[j]   (16384x1024 @ 1024x512)
__launch_bounds__(256, 1)
__global__ void fc1_gemm_kernel(const _Float16* __restrict__ ys2, const _Float16* __restrict__ wfrag,
                                const float* __restrict__ fc1b, float* __restrict__ Y1) {
  const int mb = blockIdx.x >> 3;
  const int nb = blockIdx.x & 7;
  const int tid = threadIdx.x;
  const int lane = tid & 63;
  const int w = tid >> 6;
  const int q = lane >> 4;
  const int R0 = mb * 64 + w * 16;
  const int arow = R0 + (lane & 15);           // row = u*64 + b
  const int u = arow >> 6;
  const int b = arow & 63;
  const f16x8* A = (const f16x8*)(ys2 + (size_t)(u + 1) * 65536);  // tiled [cg][b][8]
  const f16x8* W = (const f16x8*)wfrag;
  f32x4 acc[4];
  #pragma unroll
  for (int n = 0; n < 4; ++n) acc[n] = (f32x4){0.f, 0.f, 0.f, 0.f};
  #pragma unroll 4
  for (int kb = 0; kb < 32; ++kb) {
    f16x8 a = A[(kb * 4 + q) * 64 + b];
    #pragma unroll
    for (int n = 0; n < 4; ++n)
      acc[n] = __builtin_amdgcn_mfma_f32_16x16x32_f16(a, W[(((nb * 4 + n) * 32) + kb) * 64 + lane],
                                                      acc[n], 0, 0, 0);
  }
  const int rb = R0 + (q << 2);
  #pragma unroll
  for (int n = 0; n < 4; ++n) {
    int col = nb * 64 + n * 16 + (lane & 15);
    float bias = fc1b[col];
    #pragma unroll
    for (int r = 0; r < 4; ++r) {
      int R = rb + r;
      Y1[((size_t)(R & 63) * 256 + (R >> 6)) * 512 + col] = acc[n][r] + bias;
    }
  }
}

// FC2 partial reduction: 256 K-chunks of 512; part[kc][b][36]
__global__ void fc2_partial_kernel(const float* __restrict__ Y1, const float* __restrict__ fc2w,
                                   float* __restrict__ part) {
  int kc = blockIdx.x;
  int tid = threadIdx.x;
  int b = tid >> 2, qq = tid & 3;
  const float* y = Y1 + (size_t)b * 131072 + (size_t)kc * 512;
  const float* wbase = fc2w + (size_t)kc * 512 * 36 + qq * 9;
  float acc[9];
  #pragma unroll
  for (int j = 0; j < 9; ++j) acc[j] = 0.f;
  for (int k = 0; k < 512; ++k) {
    float yv = y[k];
    const float* wr = wbase + (size_t)k * 36;
    #pragma unroll
    for (int j = 0; j < 9; ++j) acc[j] = fmaf(yv, wr[j], acc[j]);
  }
  float* o = part + ((size_t)kc * 64 + b) * 36 + qq * 9;
  #pragma unroll
  for (int j = 0; j < 9; ++j) o[j] = acc[j];
}

__global__ void fc_final_kernel(const float* __restrict__ part, const float* __restrict__ fc2b,
                                const float* __restrict__ fc3w, const float* __restrict__ fc3b,
                                const float* __restrict__ fc4w, const float* __restrict__ fc4b,
                                float* __restrict__ out) {
  __shared__ float z2[64 * 36];
  __shared__ float z3[64 * 6];
  int tid = threadIdx.x;  // 384
  for (int idx = tid; idx < 64 * 36; idx += 384) {
    int b = idx / 36, m = idx % 36;
    float s = fc2b[m];
    for (int kc = 0; kc < 256; ++kc) s += part[((size_t)kc * 64 + b) * 36 + m];
    z2[idx] = s;
  }
  __syncthreads();
  {
    int b = tid / 6, n = tid % 6;
    float s = fc3b[n];
    #pragma unroll 4
    for (int m = 0; m < 36; ++m) s += z2[b * 36 + m] * fc3w[m * 6 + n];
    z3[tid] = s;
  }
  __syncthreads();
  {
    int b = tid / 6, n = tid % 6;
    float s = fc4b[n];
    #pragma unroll
    for (int m = 0; m < 6; ++m) s += z3[b * 6 + m] * fc4w[m * 6 + n];
    out[tid] = fmaxf(s, 0.0f);
  }
}

// ---------------- host ----------------

extern "C" void kernel_launch(void* const* d_in, const int* in_sizes, int n_in,
                              void* d_out, int out_size, void* d_ws, size_t ws_size,
                              hipStream_t stream) {
  const float* x    = (const float*)d_in[0];
  const float* h0   = (const float*)d_in[1];
  const float* c0   = (const float*)d_in[2];
  const float* W1   = (const float*)d_in[3];
  const float* U1   = (const float*)d_in[4];
  const float* b1   = (const float*)d_in[5];
  const float* W2   = (const float*)d_in[6];
  const float* U2   = (const float*)d_in[7];
  const float* b2   = (const float*)d_in[8];
  const float* fc1w = (const float*)d_in[9];
  const float* fc1b = (const float*)d_in[10];
  const float* fc2w = (const float*)d_in[11];
  const float* fc2b = (const float*)d_in[12];
  const float* fc3w = (const float*)d_in[13];
  const float* fc3b = (const float*)d_in[14];
  const float* fc4w = (const float*)d_in[15];
  const float* fc4b = (const float*)d_in[16];
  float* out = (float*)d_out;

  char* p = (char*)d_ws;
  auto alloc = [&](size_t bytes) { char* r = p; p += (bytes + 255) & ~(size_t)255; return r; };
  _Float16* xh    = (_Float16*)alloc(8388608ull * 2);        // x tiled f16 [t][dg][b][8]
  _Float16* wu1f  = (_Float16*)alloc(1536ull * 4096 * 2);    // [W1;U1] B-fragments, permuted cols
  _Float16* wu2f  = (_Float16*)alloc(2048ull * 4096 * 2);    // [W2;U2]
  _Float16* fc1wf = (_Float16*)alloc(1024ull * 512 * 2);     // fc1_w B-fragments
  float* b1p      = (float*)alloc(4096 * 4);
  float* b2p      = (float*)alloc(4096 * 4);
  _Float16* ys1   = (_Float16*)alloc(257ull * 65536 * 2);    // h1 slots, tiled: [0]=h0, [t+1]=h1_t
  _Float16* ys2   = (_Float16*)alloc(257ull * 65536 * 2);    // h2 slots, tiled
  float* cfin     = (float*)alloc(65536 * 4);                // c1 final [b][h] fp32
  _Float16* xg    = (_Float16*)alloc(256ull * 65536 * 4 * 2);// 128 MB: x-part gates (shared L1/L2)
  float* part     = (float*)alloc(256ull * 64 * 36 * 4);     // FC2 partials
  int* bar        = (int*)alloc(8192 * 4);                   // 2 flag regions (2048 ints each)
  float* Y1       = (float*)xg;                              // FC1 out aliases xg (dead by then)
  (void)in_sizes; (void)n_in; (void)out_size; (void)ws_size;

  prep_x_kernel<<<8388608 / 256, 256, 0, stream>>>(x, xh);
  swizzle_b_kernel<<<(256 * 48 * 64) / 256, 256, 0, stream>>>(W1, U1, 512, 1536, 4096, 4096, 1, wu1f);
  swizzle_b_kernel<<<(256 * 64 * 64) / 256, 256, 0, stream>>>(W2, U2, 1024, 2048, 4096, 4096, 1, wu2f);
  swizzle_b_kernel<<<(32 * 32 * 64) / 256, 256, 0, stream>>>(fc1w, fc1w, 1024, 1024, 512, 512, 0, fc1wf);
  prep_small_kernel<<<256, 256, 0, stream>>>(b1, b2, h0, b1p, b2p, ys1, bar);

  // Layer 1: xg1 = x@W1+b1, then recurrence (h slot0 = h0; c: c0 -> cfin)
  xg_gemm_kernel<<<512, 256, 0, stream>>>(xh, (size_t)32768, 16, wu1f, b1p, xg);
  lstm_layer_kernel<<<256, NT, 0, stream>>>(xg, ys1, ys1, wu1f, 16, c0, cfin, bar);
  // Layer 2: xg2 = ys1@W2+b2 (ys1 fully materialized), then recurrence
  xg_gemm_kernel<<<512, 256, 0, stream>>>(ys1 + 65536, (size_t)65536, 32, wu2f, b2p, xg);
  lstm_layer_kernel<<<256, NT, 0, stream>>>(xg, ys2, ys1 + (size_t)256 * 65536, wu2f, 32,
                                            cfin, nullptr, bar + 2048);

  fc1_gemm_kernel<<<2048, 256, 0, stream>>>(ys2, fc1wf, fc1b, Y1);
  fc2_partial_kernel<<<256, 256, 0, stream>>>(Y1, fc2w, part);
  fc_final_kernel<<<1, 384, 0, stream>>>(part, fc2b, fc3w, fc3b, fc4w, fc4b, out);
}

// Round 7
// 4816.854 us; speedup vs baseline: 1.9241x; 1.9241x over previous
//
#include <hip/hip_runtime.h>

// ComplexModel: 2-layer LSTM (B=64,T=256,D=512,H=1024) + FC head, MI355X gfx950.
// R7 = R6 data plane + R4/R5-style cheap sync:
//  - x-part gates precomputed by GEMM into xg (MFMA C-layout) -> recurrent kernel
//    streams NO weights (R6 proved: FETCH 1GB->153MB; the 12us/step of R3-R5 was
//    HBM re-streaming of L2-evicted weight fragments).
//  - per step: each wave sc1-stores its own 128B h patch, s_waitcnt(0),
//    ONE __syncthreads, tid0 plain sc1 flag store := t+1. NO atomic RMWs
//    (R6's packed-counter RMW storm cost ~6us/step).
//  - consumers poll the half's 128 flags per-wave (s_sleep(2) backoff), h loads
//    plain cached (single-writer lines, read-after-flag, startup acquire purge).

#define NT 256

typedef _Float16 f16x8 __attribute__((ext_vector_type(8)));
typedef _Float16 f16x4 __attribute__((ext_vector_type(4)));
typedef float f32x4 __attribute__((ext_vector_type(4)));
typedef unsigned long long u64;

__device__ __forceinline__ float sigm(float x)   { return 1.0f / (1.0f + __expf(-x)); }
__device__ __forceinline__ float tanh_f(float x) { return 1.0f - 2.0f / (__expf(2.0f * x) + 1.0f); }

// ---------------- prep kernels ----------------

// x [b][t][d] fp32 -> xh tiled f16: xh[t][dg=d/8][b][d%8]
__global__ void prep_x_kernel(const float* __restrict__ x, _Float16* __restrict__ xh) {
  int id = blockIdx.x * blockDim.x + threadIdx.x;   // 64*256*512
  int j = id & 7, b = (id >> 3) & 63, cg = (id >> 9) & 63, t = id >> 15;
  xh[id] = (_Float16)x[((size_t)b * 256 + t) * 512 + cg * 8 + j];
}

// Build MFMA B-fragment layout: dst[((nt*(K/32)+kb)*64 + lane)*8 + j] =
//   src[k = kb*32 + (lane>>4)*8 + j][col = perm(nt*16 + (lane&15))]
__global__ void swizzle_b_kernel(const float* __restrict__ src0, const float* __restrict__ src1,
                                 int k0, int K, int N, int srcStride, int permute,
                                 _Float16* __restrict__ dst) {
  int id = blockIdx.x * blockDim.x + threadIdx.x;
  int total = (N / 16) * (K / 32) * 64;
  if (id >= total) return;
  int lane = id & 63;
  int kb = (id >> 6) % (K / 32);
  int nt = id / ((K / 32) * 64);
  int kbase = kb * 32 + ((lane >> 4) << 3);
  int pc = nt * 16 + (lane & 15);
  int oc = permute ? ((pc & 3) * 1024 + (pc >> 2)) : pc;   // pc = 4*hcol + gate
  f16x8 v;
  #pragma unroll
  for (int j = 0; j < 8; ++j) {
    int k = kbase + j;
    float f = (k < k0) ? src0[(size_t)k * srcStride + oc]
                       : src1[(size_t)(k - k0) * srcStride + oc];
    v[j] = (_Float16)f;
  }
  ((f16x8*)dst)[id] = v;
}

__global__ void prep_small_kernel(const float* __restrict__ b1, const float* __restrict__ b2,
                                  const float* __restrict__ h0,
                                  float* __restrict__ b1p, float* __restrict__ b2p,
                                  _Float16* __restrict__ ys1_0, int* __restrict__ bar) {
  int i = blockIdx.x * blockDim.x + threadIdx.x;
  if (i < 4096) {
    int oc = (i & 3) * 1024 + (i >> 2);
    b1p[i] = b1[oc];
    b2p[i] = b2[oc];
  }
  if (i < 65536) {  // h0 [b][1024] -> tiled [cg][b][8]
    int j = i & 7, b = (i >> 3) & 63, cg = i >> 9;
    ys1_0[i] = (_Float16)h0[b * 1024 + cg * 8 + j];
  }
  if (i < 8192) bar[i] = 0;
}

// ---------------- x-part gate GEMM ----------------
// xg[((t*256 + gb)*256 + w*64 + lane)] (half4) = x-part pre-activation in the exact
// MFMA C-layout the lstm kernel's wave w / lane expects. gb == lstm blockIdx.
// Grid 512 = btc(2: t-halves) x gb(256). Wave w handles t = btc*128 + 4i + w.
__launch_bounds__(256, 2)
__global__ void xg_gemm_kernel(const _Float16* __restrict__ xsrc, size_t xts, int kxb,
                               const _Float16* __restrict__ bfrag, const float* __restrict__ biasp,
                               _Float16* __restrict__ xg) {
  __shared__ _Float16 Bs[2 * 32 * 64 * 8];   // 64 KB max (kxb<=32), 2 n-tiles
  const int tid = threadIdx.x;
  const int lane = tid & 63;
  const int w = tid >> 6;
  const int btc = blockIdx.x >> 8;
  const int gb = blockIdx.x & 255;
  const int mb = gb & 1, nb = gb >> 1;
  const int KB = kxb + 32;
  if (tid == 0)  // purge stale L2 lines (pre-dispatch poison) before cached reads
    (void)__hip_atomic_load((const int*)biasp, __ATOMIC_ACQUIRE, __HIP_MEMORY_SCOPE_AGENT);
  __syncthreads();
  #pragma unroll
  for (int h = 0; h < 2; ++h) {
    const uint4* s = (const uint4*)bfrag + (size_t)((2 * nb + h) * KB) * 64;  // x-part
    uint4* d = (uint4*)Bs + h * 2048;
    for (int i = tid; i < kxb * 64; i += NT) d[i] = s[i];
  }
  __syncthreads();
  const f16x8* Bv = (const f16x8*)Bs;
  const int q = lane >> 4;
  const float bias0 = biasp[(2 * nb + 0) * 16 + (lane & 15)];
  const float bias1 = biasp[(2 * nb + 1) * 16 + (lane & 15)];
  for (int i = 0; i < 32; ++i) {
    int t = btc * 128 + i * 4 + w;
    const f16x8* ax = (const f16x8*)(xsrc + (size_t)t * xts);
    f32x4 acc[4];  // tile index w' = (wn'<<1)|wm'
    acc[0] = (f32x4){bias0, bias0, bias0, bias0};
    acc[1] = (f32x4){bias0, bias0, bias0, bias0};
    acc[2] = (f32x4){bias1, bias1, bias1, bias1};
    acc[3] = (f32x4){bias1, bias1, bias1, bias1};
    #pragma unroll 8
    for (int kb = 0; kb < kxb; ++kb) {
      f16x8 a0 = ax[(kb * 4 + q) * 64 + mb * 32 + (lane & 15)];
      f16x8 a1 = ax[(kb * 4 + q) * 64 + mb * 32 + 16 + (lane & 15)];
      f16x8 b0 = Bv[kb * 64 + lane];
      f16x8 b1v = Bv[2048 + kb * 64 + lane];
      acc[0] = __builtin_amdgcn_mfma_f32_16x16x32_f16(a0, b0, acc[0], 0, 0, 0);
      acc[1] = __builtin_amdgcn_mfma_f32_16x16x32_f16(a1, b0, acc[1], 0, 0, 0);
      acc[2] = __builtin_amdgcn_mfma_f32_16x16x32_f16(a0, b1v, acc[2], 0, 0, 0);
      acc[3] = __builtin_amdgcn_mfma_f32_16x16x32_f16(a1, b1v, acc[3], 0, 0, 0);
    }
    #pragma unroll
    for (int wp = 0; wp < 4; ++wp) {
      f16x4 hv;
      #pragma unroll
      for (int j = 0; j < 4; ++j) hv[j] = (_Float16)acc[wp][j];
      ((f16x4*)xg)[((size_t)t * 256 + gb) * 256 + wp * 64 + lane] = hv;
    }
  }
}

// ---------------- persistent LSTM layer (recurrence only) ----------------
// Grid 256 = mb(2) x nb(128). Block: batches [32mb,+32) x hcols [8nb,+8).
// Waves: wm=w&1 (m-tile), wn=w>>1 (n-tile). h slot layout: [cg=col/8][b][col%8].
// Per-wave cell mapping: lane -> (b4=lane>>2, c=lane&3). Per step: wave publishes
// its 128B h patch (sc1) -> s_waitcnt(0) -> ONE __syncthreads -> tid0 stores
// flag bar[mb*128+nb] := t+1 (plain sc1). Consumers poll 128 flags per-wave.
__launch_bounds__(NT, 1)
__global__ void lstm_layer_kernel(const _Float16* __restrict__ xg,
                                  _Float16* hseq, const _Float16* __restrict__ hinit,
                                  const _Float16* __restrict__ bfrag, int kxb,
                                  const float* __restrict__ cin, float* __restrict__ cout,
                                  int* bar) {
  __shared__ _Float16 Bs[2 * 32 * 64 * 8];            // 64 KB U-part B fragments
  __shared__ __align__(16) float gt[4][16 * 20];      // per-wave gate tile (pad 20)
  __shared__ u64 hl[4][16];                           // per-wave h staging (128 B)
  const int tid = threadIdx.x;
  const int lane = tid & 63;
  const int w = tid >> 6;
  const int wm = w & 1, wn = w >> 1;
  const int blk = blockIdx.x;
  const int mb = blk & 1, nb = blk >> 1;
  const int KB = kxb + 32;

  if (tid == 0)  // purge stale L2 (poison / cross-dispatch) before cached reads
    (void)__hip_atomic_load(&bar[1024], __ATOMIC_ACQUIRE, __HIP_MEMORY_SCOPE_AGENT);
  __syncthreads();

  #pragma unroll
  for (int h = 0; h < 2; ++h) {  // stage U-part fragments
    const uint4* s = (const uint4*)bfrag + (size_t)((2 * nb + h) * KB + kxb) * 64;
    uint4* d = (uint4*)Bs + h * 2048;
    for (int i = tid; i < 2048; i += NT) d[i] = s[i];
  }
  __syncthreads();

  const f16x8* Bv = (const f16x8*)Bs;
  const int q = lane >> 4;
  const int brow = mb * 32 + wm * 16 + (lane & 15);   // A row (batch) this lane supplies
  float cc = cin[(size_t)(mb * 32 + wm * 16 + (lane >> 2)) * 1024 + nb * 8 + wn * 4 + (lane & 3)];
  float* gw = &gt[w][0];
  _Float16* hw = (_Float16*)&hl[w][0];
  const u64 hstIdx = (u64)(nb * 128 + (mb * 32 + wm * 16 + (lane & 15)) * 2 + wn);
  const u64* fp = (const u64*)bar + mb * 64 + lane;   // 128 flags of this half
  const int fidx = mb * 128 + nb;

  for (int t = 0; t < 256; ++t) {
    f16x4 xgv = ((const f16x4*)xg)[((size_t)t * 256 + blk) * 256 + w * 64 + lane];  // prefetch
    if (t) {
      for (;;) {
        u64 v = __hip_atomic_load(fp, __ATOMIC_RELAXED, __HIP_MEMORY_SCOPE_AGENT);
        if (__all(((int)v >= t) && ((int)(v >> 32) >= t))) break;
        __builtin_amdgcn_s_sleep(2);
      }
      asm volatile("" ::: "memory");  // keep h loads below the poll
    }
    f32x4 acc = {(float)xgv[0], (float)xgv[1], (float)xgv[2], (float)xgv[3]};
    const f16x8* ah = (const f16x8*)((t == 0) ? hinit : (hseq + (size_t)t * 65536));
    #pragma unroll 8
    for (int kb = 0; kb < 32; ++kb)
      acc = __builtin_amdgcn_mfma_f32_16x16x32_f16(ah[(kb * 4 + q) * 64 + brow],
                                                   Bv[(wn * 32 + kb) * 64 + lane], acc, 0, 0, 0);
    // wave-local gate regroup: write C rows, read this lane's cell (i,f,g,o)
    #pragma unroll
    for (int r = 0; r < 4; ++r) gw[(q * 4 + r) * 20 + (lane & 15)] = acc[r];
    float4 gv = *(float4*)&gw[(lane >> 2) * 20 + (lane & 3) * 4];
    cc = sigm(gv.y) * cc + sigm(gv.x) * tanh_f(gv.z);
    float hn = sigm(gv.w) * tanh_f(cc);
    hw[lane] = (_Float16)hn;                          // hw[4*b4 + c]
    u64 hv = hl[w][lane & 15];                        // 8B = cols [wn*4,+4) of batch (lane&15)
    if (lane < 16)
      __hip_atomic_store((u64*)(hseq + (size_t)(t + 1) * 65536) + hstIdx, hv,
                         __ATOMIC_RELAXED, __HIP_MEMORY_SCOPE_AGENT);
    __builtin_amdgcn_s_waitcnt(0);                    // this wave's h stores drained
    asm volatile("" ::: "memory");
    __syncthreads();                                  // all 4 waves drained
    if (t < 255 && tid == 0)
      __hip_atomic_store(&bar[fidx], t + 1, __ATOMIC_RELAXED, __HIP_MEMORY_SCOPE_AGENT);
  }
  if (cout)
    cout[(size_t)(mb * 32 + wm * 16 + (lane >> 2)) * 1024 + nb * 8 + wn * 4 + (lane & 3)] = cc;
}

// ---------------- FC head ----------------

// Y1[b][u][j] = ys2[u+1][b][:] @ fc1_w[:, j] + fc1_b[j]   (16384x1024 @ 1024x512)
__launch_bounds__(256, 1)
__global__ void fc1_gemm_kernel(const _Float16* __restrict__ ys2, const _Float16* __restrict__ wfrag,
                                const float* __restrict__ fc1b, float* __restrict__ Y1) {
  const int mb = blockIdx.x >> 3;
  const int nb = blockIdx.x & 7;
  const int tid = threadIdx.x;
  const int lane = tid & 63;
  const int w = tid >> 6;
  const int q = lane >> 4;
  const int R0 = mb * 64 + w * 16;
  const int arow = R0 + (lane & 15);           // row = u*64 + b
  const int u = arow >> 6;
  const int b = arow & 63;
  const f16x8* A = (const f16x8*)(ys2 + (size_t)(u + 1) * 65536);  // tiled [cg][b][8]
  const f16x8* W = (const f16x8*)wfrag;
  f32x4 acc[4];
  #pragma unroll
  for (int n = 0; n < 4; ++n) acc[n] = (f32x4){0.f, 0.f, 0.f, 0.f};
  #pragma unroll 4
  for (int kb = 0; kb < 32; ++kb) {
    f16x8 a = A[(kb * 4 + q) * 64 + b];
    #pragma unroll
    for (int n = 0; n < 4; ++n)
      acc[n] = __builtin_amdgcn_mfma_f32_16x16x32_f16(a, W[(((nb * 4 + n) * 32) + kb) * 64 + lane],
                                                      acc[n], 0, 0, 0);
  }
  const int rb = R0 + (q << 2);
  #pragma unroll
  for (int n = 0; n < 4; ++n) {
    int col = nb * 64 + n * 16 + (lane & 15);
    float bias = fc1b[col];
    #pragma unroll
    for (int r = 0; r < 4; ++r) {
      int R = rb + r;
      Y1[((size_t)(R & 63) * 256 + (R >> 6)) * 512 + col] = acc[n][r] + bias;
    }
  }
}

// FC2 partial reduction: 256 K-chunks of 512; part[kc][b][36]
__global__ void fc2_partial_kernel(const float* __restrict__ Y1, const float* __restrict__ fc2w,
                                   float* __restrict__ part) {
  int kc = blockIdx.x;
  int tid = threadIdx.x;
  int b = tid >> 2, qq = tid & 3;
  const float* y = Y1 + (size_t)b * 131072 + (size_t)kc * 512;
  const float* wbase = fc2w + (size_t)kc * 512 * 36 + qq * 9;
  float acc[9];
  #pragma unroll
  for (int j = 0; j < 9; ++j) acc[j] = 0.f;
  for (int k = 0; k < 512; ++k) {
    float yv = y[k];
    const float* wr = wbase + (size_t)k * 36;
    #pragma unroll
    for (int j = 0; j < 9; ++j) acc[j] = fmaf(yv, wr[j], acc[j]);
  }
  float* o = part + ((size_t)kc * 64 + b) * 36 + qq * 9;
  #pragma unroll
  for (int j = 0; j < 9; ++j) o[j] = acc[j];
}

__global__ void fc_final_kernel(const float* __restrict__ part, const float* __restrict__ fc2b,
                                const float* __restrict__ fc3w, const float* __restrict__ fc3b,
                                const float* __restrict__ fc4w, const float* __restrict__ fc4b,
                                float* __restrict__ out) {
  __shared__ float z2[64 * 36];
  __shared__ float z3[64 * 6];
  int tid = threadIdx.x;  // 384
  for (int idx = tid; idx < 64 * 36; idx += 384) {
    int b = idx / 36, m = idx % 36;
    float s = fc2b[m];
    for (int kc = 0; kc < 256; ++kc) s += part[((size_t)kc * 64 + b) * 36 + m];
    z2[idx] = s;
  }
  __syncthreads();
  {
    int b = tid / 6, n = tid % 6;
    float s = fc3b[n];
    #pragma unroll 4
    for (int m = 0; m < 36; ++m) s += z2[b * 36 + m] * fc3w[m * 6 + n];
    z3[tid] = s;
  }
  __syncthreads();
  {
    int b = tid / 6, n = tid % 6;
    float s = fc4b[n];
    #pragma unroll
    for (int m = 0; m < 6; ++m) s += z3[b * 6 + m] * fc4w[m * 6 + n];
    out[tid] = fmaxf(s, 0.0f);
  }
}

// ---------------- host ----------------

extern "C" void kernel_launch(void* const* d_in, const int* in_sizes, int n_in,
                              void* d_out, int out_size, void* d_ws, size_t ws_size,
                              hipStream_t stream) {
  const float* x    = (const float*)d_in[0];
  const float* h0   = (const float*)d_in[1];
  const float* c0   = (const float*)d_in[2];
  const float* W1   = (const float*)d_in[3];
  const float* U1   = (const float*)d_in[4];
  const float* b1   = (const float*)d_in[5];
  const float* W2   = (const float*)d_in[6];
  const float* U2   = (const float*)d_in[7];
  const float* b2   = (const float*)d_in[8];
  const float* fc1w = (const float*)d_in[9];
  const float* fc1b = (const float*)d_in[10];
  const float* fc2w = (const float*)d_in[11];
  const float* fc2b = (const float*)d_in[12];
  const float* fc3w = (const float*)d_in[13];
  const float* fc3b = (const float*)d_in[14];
  const float* fc4w = (const float*)d_in[15];
  const float* fc4b = (const float*)d_in[16];
  float* out = (float*)d_out;

  char* p = (char*)d_ws;
  auto alloc = [&](size_t bytes) { char* r = p; p += (bytes + 255) & ~(size_t)255; return r; };
  _Float16* xh    = (_Float16*)alloc(8388608ull * 2);        // x tiled f16 [t][dg][b][8]
  _Float16* wu1f  = (_Float16*)alloc(1536ull * 4096 * 2);    // [W1;U1] B-fragments, permuted cols
  _Float16* wu2f  = (_Float16*)alloc(2048ull * 4096 * 2);    // [W2;U2]
  _Float16* fc1wf = (_Float16*)alloc(1024ull * 512 * 2);     // fc1_w B-fragments
  float* b1p      = (float*)alloc(4096 * 4);
  float* b2p      = (float*)alloc(4096 * 4);
  _Float16* ys1   = (_Float16*)alloc(257ull * 65536 * 2);    // h1 slots, tiled: [0]=h0, [t+1]=h1_t
  _Float16* ys2   = (_Float16*)alloc(257ull * 65536 * 2);    // h2 slots, tiled
  float* cfin     = (float*)alloc(65536 * 4);                // c1 final [b][h] fp32
  _Float16* xg    = (_Float16*)alloc(256ull * 65536 * 4 * 2);// 128 MB: x-part gates
  float* part     = (float*)alloc(256ull * 64 * 36 * 4);     // FC2 partials
  int* bar        = (int*)alloc(8192 * 4);                   // 2 flag regions (2048 ints each)
  float* Y1       = (float*)xg;                              // FC1 out aliases xg (dead by then)
  (void)in_sizes; (void)n_in; (void)out_size; (void)ws_size;

  prep_x_kernel<<<8388608 / 256, 256, 0, stream>>>(x, xh);
  swizzle_b_kernel<<<(256 * 48 * 64) / 256, 256, 0, stream>>>(W1, U1, 512, 1536, 4096, 4096, 1, wu1f);
  swizzle_b_kernel<<<(256 * 64 * 64) / 256, 256, 0, stream>>>(W2, U2, 1024, 2048, 4096, 4096, 1, wu2f);
  swizzle_b_kernel<<<(32 * 32 * 64) / 256, 256, 0, stream>>>(fc1w, fc1w, 1024, 1024, 512, 512, 0, fc1wf);
  prep_small_kernel<<<256, 256, 0, stream>>>(b1, b2, h0, b1p, b2p, ys1, bar);

  // Layer 1: xg1 = x@W1+b1, then recurrence (h slot0 = h0; c: c0 -> cfin)
  xg_gemm_kernel<<<512, 256, 0, stream>>>(xh, (size_t)32768, 16, wu1f, b1p, xg);
  lstm_layer_kernel<<<256, NT, 0, stream>>>(xg, ys1, ys1, wu1f, 16, c0, cfin, bar);
  // Layer 2: xg2 = ys1@W2+b2 (ys1 fully materialized), then recurrence
  xg_gemm_kernel<<<512, 256, 0, stream>>>(ys1 + 65536, (size_t)65536, 32, wu2f, b2p, xg);
  lstm_layer_kernel<<<256, NT, 0, stream>>>(xg, ys2, ys1 + (size_t)256 * 65536, wu2f, 32,
                                            cfin, nullptr, bar + 2048);

  fc1_gemm_kernel<<<2048, 256, 0, stream>>>(ys2, fc1wf, fc1b, Y1);
  fc2_partial_kernel<<<256, 256, 0, stream>>>(Y1, fc2w, part);
  fc_final_kernel<<<1, 384, 0, stream>>>(part, fc2b, fc3w, fc3b, fc4w, fc4b, out);
}